// Round 5
// baseline (135.948 us; speedup 1.0000x reference)
//
#include <hip/hip_runtime.h>
#include <hip/hip_bf16.h>
#include <math.h>

#define FRAME_LEN 882
#define FRAME_HOP 441
#define NFFT 2048
#define NFRAMES 999
#define NBATCH 16
#define NMEL 60
#define WAVE_LEN 441000
#define PRE_EMPH 0.97f
#define EPS 1e-10f
#define NROWS (NBATCH * NFRAMES)     // 15984 = 999*16
#define KPAD 1056                    // 33*32; >=1025, multiple of 32 and 8
#define PI_F 3.14159265358979323846f

// LDS float2 index padding: +1 float2 per 16 -> breaks power-of-2 stride conflicts
#define PADI(i) ((i) + ((i) >> 4))

__device__ __forceinline__ float2 cadd(float2 a, float2 b){ return make_float2(a.x+b.x, a.y+b.y); }
__device__ __forceinline__ float2 csub(float2 a, float2 b){ return make_float2(a.x-b.x, a.y-b.y); }
__device__ __forceinline__ float2 cmul(float2 a, float2 b){ return make_float2(a.x*b.x - a.y*b.y, a.x*b.y + a.y*b.x); }
__device__ __forceinline__ float2 rotni(float2 z){ return make_float2(z.y, -z.x); }  // z * (-i)

// Three consecutive DIF radix-2 stages (halves 4S,2S,S) in registers.
// Thread owns e_k = q*8S + k*S + r (k=0..7). ALL twiddles derive from
// t1 = e^{-i*pi*r/(4S)}: stage-1 twiddles are t1 * e^{-i*pi*k/4}
// (w_{k+2} = -i*w_k free), stage-2 = {t1^2, -i*t1^2}, stage-3 = t1^4.
__device__ __forceinline__ void dif_group8(float2* x, float2 t1) {
  const float2 C41 = make_float2(0.7071067812f, -0.7071067812f);
  float2 w0 = t1, w1 = cmul(t1, C41), w2 = rotni(w0), w3 = rotni(w1);
  float2 u, v;
  u=x[0]; v=x[4]; x[0]=cadd(u,v); x[4]=cmul(csub(u,v), w0);
  u=x[1]; v=x[5]; x[1]=cadd(u,v); x[5]=cmul(csub(u,v), w1);
  u=x[2]; v=x[6]; x[2]=cadd(u,v); x[6]=cmul(csub(u,v), w2);
  u=x[3]; v=x[7]; x[3]=cadd(u,v); x[7]=cmul(csub(u,v), w3);
  float2 t2 = cmul(t1, t1), t2r = rotni(t2);
  u=x[0]; v=x[2]; x[0]=cadd(u,v); x[2]=cmul(csub(u,v), t2);
  u=x[1]; v=x[3]; x[1]=cadd(u,v); x[3]=cmul(csub(u,v), t2r);
  u=x[4]; v=x[6]; x[4]=cadd(u,v); x[6]=cmul(csub(u,v), t2);
  u=x[5]; v=x[7]; x[5]=cadd(u,v); x[7]=cmul(csub(u,v), t2r);
  float2 t4 = cmul(t2, t2);
  u=x[0]; v=x[1]; x[0]=cadd(u,v); x[1]=cmul(csub(u,v), t4);
  u=x[2]; v=x[3]; x[2]=cadd(u,v); x[3]=cmul(csub(u,v), t4);
  u=x[4]; v=x[5]; x[4]=cadd(u,v); x[5]=cmul(csub(u,v), t4);
  u=x[6]; v=x[7]; x[6]=cadd(u,v); x[7]=cmul(csub(u,v), t4);
}

// Final two DIF stages (halves 2,1) on 4 consecutive elements: twiddles 1, -i.
__device__ __forceinline__ void dif_radix4(float2* x) {
  float2 y0 = cadd(x[0], x[2]);
  float2 y2 = csub(x[0], x[2]);
  float2 y1 = cadd(x[1], x[3]);
  float2 t3 = csub(x[1], x[3]);
  float2 y3 = rotni(t3);
  x[0] = cadd(y0, y1); x[1] = csub(y0, y1);
  x[2] = cadd(y2, y3); x[3] = csub(y2, y3);
}

// Kernel 1: 256 threads per block, one frame-pair per block. Two real frames
// packed as real+imag of one 2048-pt complex DIF FFT (natural in, bit-reversed
// out). Radix-8 register blocking (Round-3 skeleton), but only ONE sincos per
// twiddle group (t1-factorization) + window via complex recurrence:
// 4 sincos/thread total (was ~29). Writes bf16 power spectra, K-padded.
__global__ __launch_bounds__(256) void fft_pow_kernel(
    const float* __restrict__ wav, __hip_bfloat16* __restrict__ powr)
{
  __shared__ float2 lds[NFFT + (NFFT >> 4)];   // 2176 float2 = 17.4 KB
  const int t  = threadIdx.x;
  const int t0 = 2 * blockIdx.x, t1f = t0 + 1;
  const bool has1 = (t1f < NFRAMES);
  const int b = blockIdx.y;
  const float* w = wav + (size_t)b * WAVE_LEN;
  const int s0 = t0 * FRAME_HOP, s1 = t1f * FRAME_HOP;

  float2 x[8];
  // ---- load + pre-emphasis + Hamming: element i = k*256 + t (natural order)
  // win(i) = 0.54 - 0.46*cos(2*pi*i/881); cos via one sincos + recurrence.
  {
    float sB, cB, sD, cD;
    __sincosf(6.283185307179586f * (float)t / 881.0f, &sB, &cB);
    __sincosf(6.283185307179586f * 256.0f / 881.0f, &sD, &cD);
    float2 cur  = make_float2(cB, sB);
    float2 step = make_float2(cD, sD);
#pragma unroll
    for (int k = 0; k < 8; ++k) {
      int i = k * 256 + t;
      float v1 = 0.f, v2 = 0.f;
      if (i < FRAME_LEN) {
        float win = 0.54f - 0.46f * cur.x;
        int s = s0 + i;
        float e1 = (s > 0) ? (w[s] - PRE_EMPH * w[s - 1]) : w[s];
        v1 = e1 * win;
        if (has1) {
          int ss = s1 + i;                    // ss >= 441 > 0 always
          v2 = (w[ss] - PRE_EMPH * w[ss - 1]) * win;
        }
      }
      x[k] = make_float2(v1, v2);
      cur = cmul(cur, step);
    }
  }

  // ---- G0: halves 1024,512,256 (S=256, r=t): t1 = e^{-i*pi*t/1024}
  {
    float sA, cA;
    __sincosf(-PI_F * (float)t / 1024.0f, &sA, &cA);
    dif_group8(x, make_float2(cA, sA));
  }
#pragma unroll
  for (int k = 0; k < 8; ++k) lds[PADI(k * 256 + t)] = x[k];
  __syncthreads();

  // ---- G1: halves 128,64,32 (S=32): t1 = e^{-i*pi*r/128}, r = t&31
  {
    const int q = t >> 5, r = t & 31;
#pragma unroll
    for (int k = 0; k < 8; ++k) x[k] = lds[PADI(q * 256 + k * 32 + r)];
    float sA, cA;
    __sincosf(-PI_F * (float)r / 128.0f, &sA, &cA);
    dif_group8(x, make_float2(cA, sA));
    __syncthreads();
#pragma unroll
    for (int k = 0; k < 8; ++k) lds[PADI(q * 256 + k * 32 + r)] = x[k];
  }
  __syncthreads();

  // ---- G2: halves 16,8,4 (S=4): t1 = e^{-i*pi*r/16}, r = t&3 -> const table
  {
    const int q = t >> 2, r = t & 3;
#pragma unroll
    for (int k = 0; k < 8; ++k) x[k] = lds[PADI(q * 32 + k * 4 + r)];
    // e^{-i*pi*r/16}, r = 0..3
    float tc = (r == 0) ? 1.0f : (r == 1) ? 0.980785280f : (r == 2) ? 0.923879533f : 0.831469612f;
    float ts = (r == 0) ? 0.0f : (r == 1) ? -0.195090322f : (r == 2) ? -0.382683432f : -0.555570233f;
    dif_group8(x, make_float2(tc, ts));
    __syncthreads();
#pragma unroll
    for (int k = 0; k < 8; ++k) lds[PADI(q * 32 + k * 4 + r)] = x[k];
  }
  __syncthreads();

  // ---- G3: halves 2,1 — two radix-4 groups of 4 consecutive elements
  {
    float2 xa[4], xb[4];
#pragma unroll
    for (int j = 0; j < 4; ++j) {
      xa[j] = lds[PADI(4 * t + j)];
      xb[j] = lds[PADI(4 * (t + 256) + j)];
    }
    dif_radix4(xa);
    dif_radix4(xb);
    __syncthreads();
#pragma unroll
    for (int j = 0; j < 4; ++j) {
      lds[PADI(4 * t + j)] = xa[j];
      lds[PADI(4 * (t + 256) + j)] = xb[j];
    }
  }
  __syncthreads();

  // ---- power separation + bf16 store (spectrum is bit-reversed in LDS)
  const size_t row0 = (size_t)b * NFRAMES + t0;
  __hip_bfloat16* p0 = powr + row0 * KPAD;
  __hip_bfloat16* p1 = powr + (row0 + 1) * KPAD;
#pragma unroll
  for (int c = 0; c < 5; ++c) {
    int f = t + 256 * c;
    bool valid = (c < 4) || (t == 0);
    if (c == 4) f = 1024;
    if (valid) {
      int j1 = (int)(__brev((unsigned)f) >> 21);
      int j2 = (int)(__brev((unsigned)((NFFT - f) & (NFFT - 1))) >> 21);
      float2 z = lds[PADI(j1)];
      float2 y = lds[PADI(j2)];
      float f1r = z.x + y.x, f1i = z.y - y.y;
      float f2r = z.y + y.y, f2i = y.x - z.x;
      float pw1 = 0.25f * (f1r * f1r + f1i * f1i);
      float pw2 = 0.25f * (f2r * f2r + f2i * f2i);
      p0[f] = __float2bfloat16(pw1);
      if (has1) p1[f] = __float2bfloat16(pw2);
    }
  }
  // zero the K pads (1025..KPAD-1)
  if (t < KPAD - 1025) {
    p0[1025 + t] = __float2bfloat16(0.f);
    if (has1) p1[1025 + t] = __float2bfloat16(0.f);
  }
}

// Kernel 0: filt (60x1025 f32) -> bf16, padded to 64 rows x KPAD cols, pads zero.
__global__ __launch_bounds__(256) void filtconv_kernel(
    const float* __restrict__ filt, __hip_bfloat16* __restrict__ filtb)
{
  const int m = blockIdx.x;  // 0..63
  for (int k = threadIdx.x; k < KPAD; k += 256) {
    float v = (m < NMEL && k < 1025) ? filt[m * 1025 + k] : 0.f;
    filtb[(size_t)m * KPAD + k] = __float2bfloat16(v);
  }
}

// Kernel 2: mel GEMM via MFMA, re-tiled for latency hiding.
// Block = 1 row-tile of 16 rows (999 blocks, 15984 = 999*16 exactly);
// wave w = mel-tile [16w, 16w+16). 3996 waves (~16/CU), 1 acc per wave,
// 2 loads + 1 MFMA per K-step, unroll 3 so loads batch ahead of MFMAs.
// A chunk is shared by the 4 waves through L1.
typedef __attribute__((ext_vector_type(8))) short short8x;
typedef __attribute__((ext_vector_type(4))) float float4x;

__global__ __launch_bounds__(256) void melgemm_kernel(
    const __hip_bfloat16* __restrict__ powr,
    const __hip_bfloat16* __restrict__ filtb,
    float* __restrict__ logmel)
{
  const int wave = threadIdx.x >> 6, lane = threadIdx.x & 63;
  const int row0 = blockIdx.x * 16;
  const int lrow = lane & 15, kgrp = lane >> 4;   // frag: [m=lane&15][k=(lane>>4)*8+j]

  const __hip_bfloat16* ap = powr + (size_t)(row0 + lrow) * KPAD + kgrp * 8;
  const __hip_bfloat16* bp = filtb + (size_t)(wave * 16 + lrow) * KPAD + kgrp * 8;

  float4x acc = {0.f, 0.f, 0.f, 0.f};
#pragma unroll 3
  for (int kk = 0; kk < 33; ++kk) {
    short8x a = *(const short8x*)ap;
    short8x bf = *(const short8x*)bp;
    acc = __builtin_amdgcn_mfma_f32_16x16x32_bf16(a, bf, acc, 0, 0, 0);
    ap += 32; bp += 32;
  }

  // C/D layout (m89-verified): col = lane&15, row = (lane>>4)*4 + reg
  const int mel = wave * 16 + (lane & 15);
  const int rsub = (lane >> 4) * 4;
  if (mel < NMEL) {
#pragma unroll
    for (int reg = 0; reg < 4; ++reg) {
      int row = row0 + rsub + reg;
      logmel[(size_t)row * NMEL + mel] = __logf(acc[reg] + EPS);
    }
  }
}

// Kernel 3: stats — one block per (feature j, batch b); two-pass mean/std.
__global__ __launch_bounds__(256) void stats_kernel(
    const float* __restrict__ logmel, float* __restrict__ out)
{
  __shared__ float red[4];
  const int j   = blockIdx.x;   // 0..89
  const int b   = blockIdx.y;   // 0..15
  const int tid = threadIdx.x;
  const float* lm = logmel + (size_t)b * NFRAMES * NMEL;
  const float inv_sq2 = 0.7071067811865475f;

  float fv[4];
  int   nf = 0;
#pragma unroll
  for (int r = 0; r < 4; ++r) {
    int tt = tid + (r << 8);
    if (tt < NFRAMES) {
      float v;
      if (j < 30) {
        int m = j;
        v = (lm[tt * NMEL + 2 * m] + lm[tt * NMEL + 2 * m + 1]) * inv_sq2;
      } else if (j < 60) {
        int m  = j - 30;
        int tp = (tt + 1 > NFRAMES - 1) ? (NFRAMES - 1) : (tt + 1);
        int tm = (tt - 1 < 0) ? 0 : (tt - 1);
        float ca_p = (lm[tp * NMEL + 2 * m] + lm[tp * NMEL + 2 * m + 1]) * inv_sq2;
        float ca_m = (lm[tm * NMEL + 2 * m] + lm[tm * NMEL + 2 * m + 1]) * inv_sq2;
        v = ca_p - ca_m;
      } else {
        int m = j - 60;
        v = (lm[tt * NMEL + 2 * m] - lm[tt * NMEL + 2 * m + 1]) * inv_sq2;
      }
      fv[nf++] = v;
    }
  }

  float s = 0.f;
  for (int r = 0; r < nf; ++r) s += fv[r];
  for (int o = 32; o > 0; o >>= 1) s += __shfl_xor(s, o, 64);
  if ((tid & 63) == 0) red[tid >> 6] = s;
  __syncthreads();
  float mean = (red[0] + red[1] + red[2] + red[3]) / (float)NFRAMES;
  __syncthreads();

  float s2 = 0.f;
  for (int r = 0; r < nf; ++r) { float d = fv[r] - mean; s2 += d * d; }
  for (int o = 32; o > 0; o >>= 1) s2 += __shfl_xor(s2, o, 64);
  if ((tid & 63) == 0) red[tid >> 6] = s2;
  __syncthreads();
  float var = (red[0] + red[1] + red[2] + red[3]) / (float)(NFRAMES - 1);

  if (tid == 0) {
    out[b * 180 + j]      = mean;
    out[b * 180 + 90 + j] = sqrtf(var);
  }
}

extern "C" void kernel_launch(void* const* d_in, const int* in_sizes, int n_in,
                              void* d_out, int out_size, void* d_ws, size_t ws_size,
                              hipStream_t stream) {
  const float* wav  = (const float*)d_in[0];   // (16, 441000) f32
  const float* filt = (const float*)d_in[1];   // (60, 1025) f32
  float* out = (float*)d_out;                  // (16, 180) f32

  // ws layout (bytes): power bf16 [NROWS][KPAD], filt bf16 [64][KPAD], logmel f32 [NROWS][60]
  unsigned char* ws = (unsigned char*)d_ws;
  __hip_bfloat16* powr  = (__hip_bfloat16*)(ws);
  size_t off = (size_t)NROWS * KPAD * 2;                      // 33,758,208
  __hip_bfloat16* filtb = (__hip_bfloat16*)(ws + off);
  off += (size_t)64 * KPAD * 2;                               // +135,168
  float* logmel = (float*)(ws + off);                         // +3,836,160 => ~37.7 MB

  filtconv_kernel<<<64, 256, 0, stream>>>(filt, filtb);
  fft_pow_kernel<<<dim3((NFRAMES + 1) / 2, NBATCH), 256, 0, stream>>>(wav, powr);
  melgemm_kernel<<<NROWS / 16, 256, 0, stream>>>(powr, filtb, logmel);
  stats_kernel<<<dim3(90, NBATCH), 256, 0, stream>>>(logmel, out);
}

// Round 6
// 128.287 us; speedup vs baseline: 1.0597x; 1.0597x over previous
//
#include <hip/hip_runtime.h>
#include <hip/hip_bf16.h>
#include <math.h>

#define FRAME_LEN 882
#define FRAME_HOP 441
#define NFFT 2048
#define NFRAMES 999
#define NBATCH 16
#define NMEL 60
#define WAVE_LEN 441000
#define PRE_EMPH 0.97f
#define EPS 1e-10f
#define NROWS (NBATCH * NFRAMES)     // 15984 = 999*16
#define KPAD 1056                    // 33*32; >=1025, multiple of 32 and 8
#define PI_F 3.14159265358979323846f

// LDS float2 index padding: +1 float2 per 16 -> breaks power-of-2 stride conflicts
#define PADI(i) ((i) + ((i) >> 4))

__device__ __forceinline__ float2 cadd(float2 a, float2 b){ return make_float2(a.x+b.x, a.y+b.y); }
__device__ __forceinline__ float2 csub(float2 a, float2 b){ return make_float2(a.x-b.x, a.y-b.y); }
__device__ __forceinline__ float2 cmul(float2 a, float2 b){ return make_float2(a.x*b.x - a.y*b.y, a.x*b.y + a.y*b.x); }
__device__ __forceinline__ float2 rotni(float2 z){ return make_float2(z.y, -z.x); }  // z * (-i)

// Three consecutive DIF radix-2 stages (halves 4S,2S,S) in registers.
// Thread owns e_k = q*8S + k*S + r (k=0..7). ALL twiddles derive from
// t1 = e^{-i*pi*r/(4S)}.
__device__ __forceinline__ void dif_group8(float2* x, float2 t1) {
  const float2 C41 = make_float2(0.7071067812f, -0.7071067812f);
  float2 w0 = t1, w1 = cmul(t1, C41), w2 = rotni(w0), w3 = rotni(w1);
  float2 u, v;
  u=x[0]; v=x[4]; x[0]=cadd(u,v); x[4]=cmul(csub(u,v), w0);
  u=x[1]; v=x[5]; x[1]=cadd(u,v); x[5]=cmul(csub(u,v), w1);
  u=x[2]; v=x[6]; x[2]=cadd(u,v); x[6]=cmul(csub(u,v), w2);
  u=x[3]; v=x[7]; x[3]=cadd(u,v); x[7]=cmul(csub(u,v), w3);
  float2 t2 = cmul(t1, t1), t2r = rotni(t2);
  u=x[0]; v=x[2]; x[0]=cadd(u,v); x[2]=cmul(csub(u,v), t2);
  u=x[1]; v=x[3]; x[1]=cadd(u,v); x[3]=cmul(csub(u,v), t2r);
  u=x[4]; v=x[6]; x[4]=cadd(u,v); x[6]=cmul(csub(u,v), t2);
  u=x[5]; v=x[7]; x[5]=cadd(u,v); x[7]=cmul(csub(u,v), t2r);
  float2 t4 = cmul(t2, t2);
  u=x[0]; v=x[1]; x[0]=cadd(u,v); x[1]=cmul(csub(u,v), t4);
  u=x[2]; v=x[3]; x[2]=cadd(u,v); x[3]=cmul(csub(u,v), t4);
  u=x[4]; v=x[5]; x[4]=cadd(u,v); x[5]=cmul(csub(u,v), t4);
  u=x[6]; v=x[7]; x[6]=cadd(u,v); x[7]=cmul(csub(u,v), t4);
}

// Final two DIF stages (halves 2,1) on 4 consecutive elements: twiddles 1, -i.
__device__ __forceinline__ void dif_radix4(float2* x) {
  float2 y0 = cadd(x[0], x[2]);
  float2 y2 = csub(x[0], x[2]);
  float2 y1 = cadd(x[1], x[3]);
  float2 t3 = csub(x[1], x[3]);
  float2 y3 = rotni(t3);
  x[0] = cadd(y0, y1); x[1] = csub(y0, y1);
  x[2] = cadd(y2, y3); x[3] = csub(y2, y3);
}

// Kernel 1 (unchanged from R5): one frame-pair per 256-thread block; two real
// frames packed into one 2048-pt complex DIF FFT; t1-factorized twiddles
// (4 sincos/thread); bf16 power spectra out, K-padded.
__global__ __launch_bounds__(256) void fft_pow_kernel(
    const float* __restrict__ wav, __hip_bfloat16* __restrict__ powr)
{
  __shared__ float2 lds[NFFT + (NFFT >> 4)];   // 2176 float2 = 17.4 KB
  const int t  = threadIdx.x;
  const int t0 = 2 * blockIdx.x, t1f = t0 + 1;
  const bool has1 = (t1f < NFRAMES);
  const int b = blockIdx.y;
  const float* w = wav + (size_t)b * WAVE_LEN;
  const int s0 = t0 * FRAME_HOP, s1 = t1f * FRAME_HOP;

  float2 x[8];
  {
    float sB, cB, sD, cD;
    __sincosf(6.283185307179586f * (float)t / 881.0f, &sB, &cB);
    __sincosf(6.283185307179586f * 256.0f / 881.0f, &sD, &cD);
    float2 cur  = make_float2(cB, sB);
    float2 step = make_float2(cD, sD);
#pragma unroll
    for (int k = 0; k < 8; ++k) {
      int i = k * 256 + t;
      float v1 = 0.f, v2 = 0.f;
      if (i < FRAME_LEN) {
        float win = 0.54f - 0.46f * cur.x;
        int s = s0 + i;
        float e1 = (s > 0) ? (w[s] - PRE_EMPH * w[s - 1]) : w[s];
        v1 = e1 * win;
        if (has1) {
          int ss = s1 + i;
          v2 = (w[ss] - PRE_EMPH * w[ss - 1]) * win;
        }
      }
      x[k] = make_float2(v1, v2);
      cur = cmul(cur, step);
    }
  }

  {
    float sA, cA;
    __sincosf(-PI_F * (float)t / 1024.0f, &sA, &cA);
    dif_group8(x, make_float2(cA, sA));
  }
#pragma unroll
  for (int k = 0; k < 8; ++k) lds[PADI(k * 256 + t)] = x[k];
  __syncthreads();

  {
    const int q = t >> 5, r = t & 31;
#pragma unroll
    for (int k = 0; k < 8; ++k) x[k] = lds[PADI(q * 256 + k * 32 + r)];
    float sA, cA;
    __sincosf(-PI_F * (float)r / 128.0f, &sA, &cA);
    dif_group8(x, make_float2(cA, sA));
    __syncthreads();
#pragma unroll
    for (int k = 0; k < 8; ++k) lds[PADI(q * 256 + k * 32 + r)] = x[k];
  }
  __syncthreads();

  {
    const int q = t >> 2, r = t & 3;
#pragma unroll
    for (int k = 0; k < 8; ++k) x[k] = lds[PADI(q * 32 + k * 4 + r)];
    float tc = (r == 0) ? 1.0f : (r == 1) ? 0.980785280f : (r == 2) ? 0.923879533f : 0.831469612f;
    float ts = (r == 0) ? 0.0f : (r == 1) ? -0.195090322f : (r == 2) ? -0.382683432f : -0.555570233f;
    dif_group8(x, make_float2(tc, ts));
    __syncthreads();
#pragma unroll
    for (int k = 0; k < 8; ++k) lds[PADI(q * 32 + k * 4 + r)] = x[k];
  }
  __syncthreads();

  {
    float2 xa[4], xb[4];
#pragma unroll
    for (int j = 0; j < 4; ++j) {
      xa[j] = lds[PADI(4 * t + j)];
      xb[j] = lds[PADI(4 * (t + 256) + j)];
    }
    dif_radix4(xa);
    dif_radix4(xb);
    __syncthreads();
#pragma unroll
    for (int j = 0; j < 4; ++j) {
      lds[PADI(4 * t + j)] = xa[j];
      lds[PADI(4 * (t + 256) + j)] = xb[j];
    }
  }
  __syncthreads();

  const size_t row0 = (size_t)b * NFRAMES + t0;
  __hip_bfloat16* p0 = powr + row0 * KPAD;
  __hip_bfloat16* p1 = powr + (row0 + 1) * KPAD;
#pragma unroll
  for (int c = 0; c < 5; ++c) {
    int f = t + 256 * c;
    bool valid = (c < 4) || (t == 0);
    if (c == 4) f = 1024;
    if (valid) {
      int j1 = (int)(__brev((unsigned)f) >> 21);
      int j2 = (int)(__brev((unsigned)((NFFT - f) & (NFFT - 1))) >> 21);
      float2 z = lds[PADI(j1)];
      float2 y = lds[PADI(j2)];
      float f1r = z.x + y.x, f1i = z.y - y.y;
      float f2r = z.y + y.y, f2i = y.x - z.x;
      float pw1 = 0.25f * (f1r * f1r + f1i * f1i);
      float pw2 = 0.25f * (f2r * f2r + f2i * f2i);
      p0[f] = __float2bfloat16(pw1);
      if (has1) p1[f] = __float2bfloat16(pw2);
    }
  }
  if (t < KPAD - 1025) {
    p0[1025 + t] = __float2bfloat16(0.f);
    if (has1) p1[1025 + t] = __float2bfloat16(0.f);
  }
}

// Kernel 0: filt (60x1025 f32) -> bf16, padded to 64 rows x KPAD cols.
__global__ __launch_bounds__(256) void filtconv_kernel(
    const float* __restrict__ filt, __hip_bfloat16* __restrict__ filtb)
{
  const int m = blockIdx.x;  // 0..63
  for (int k = threadIdx.x; k < KPAD; k += 256) {
    float v = (m < NMEL && k < 1025) ? filt[m * 1025 + k] : 0.f;
    filtb[(size_t)m * KPAD + k] = __float2bfloat16(v);
  }
}

// Kernel 2: mel GEMM via MFMA. Block = 16-row tile (999 blocks); wave = mel
// tile. TWO independent K-chains (kk, kk+16) for 2x MFMA/load ILP. Output is
// written TRANSPOSED: logmelT[mel][row] (per block, each mel's 16 rows pack
// into one 64-B line) so the stats kernel reads coalesced.
typedef __attribute__((ext_vector_type(8))) short short8x;
typedef __attribute__((ext_vector_type(4))) float float4x;

__global__ __launch_bounds__(256) void melgemm_kernel(
    const __hip_bfloat16* __restrict__ powr,
    const __hip_bfloat16* __restrict__ filtb,
    float* __restrict__ logmelT)
{
  const int wave = threadIdx.x >> 6, lane = threadIdx.x & 63;
  const int row0 = blockIdx.x * 16;
  const int lrow = lane & 15, kgrp = lane >> 4;   // frag: [m=lane&15][k=(lane>>4)*8+j]

  const __hip_bfloat16* ap = powr + (size_t)(row0 + lrow) * KPAD + kgrp * 8;
  const __hip_bfloat16* bp = filtb + (size_t)(wave * 16 + lrow) * KPAD + kgrp * 8;

  float4x acc0 = {0.f, 0.f, 0.f, 0.f};
  float4x acc1 = {0.f, 0.f, 0.f, 0.f};
#pragma unroll 4
  for (int kk = 0; kk < 16; ++kk) {
    short8x a0 = *(const short8x*)(ap + kk * 32);
    short8x b0 = *(const short8x*)(bp + kk * 32);
    short8x a1 = *(const short8x*)(ap + (kk + 16) * 32);
    short8x b1 = *(const short8x*)(bp + (kk + 16) * 32);
    acc0 = __builtin_amdgcn_mfma_f32_16x16x32_bf16(a0, b0, acc0, 0, 0, 0);
    acc1 = __builtin_amdgcn_mfma_f32_16x16x32_bf16(a1, b1, acc1, 0, 0, 0);
  }
  {
    short8x a = *(const short8x*)(ap + 32 * 32);
    short8x bf = *(const short8x*)(bp + 32 * 32);
    acc0 = __builtin_amdgcn_mfma_f32_16x16x32_bf16(a, bf, acc0, 0, 0, 0);
  }

  // C/D layout (m89-verified): col = lane&15, row = (lane>>4)*4 + reg
  const int mel = wave * 16 + (lane & 15);
  const int rsub = (lane >> 4) * 4;
  if (mel < NMEL) {
#pragma unroll
    for (int reg = 0; reg < 4; ++reg) {
      int row = row0 + rsub + reg;
      float vv = acc0[reg] + acc1[reg];
      logmelT[(size_t)mel * NROWS + row] = __logf(vv + EPS);
    }
  }
}

// Kernel 3: stats on TRANSPOSED logmel — one block per (feature j, batch b);
// lane <-> frame, fully coalesced 4-B reads; static per-thread registers
// (no dynamically-indexed array -> no scratch); two-pass mean/std (ddof=1).
__global__ __launch_bounds__(256) void stats_kernel(
    const float* __restrict__ lmT, float* __restrict__ out)
{
  __shared__ float red[4];
  const int j   = blockIdx.x;   // 0..89
  const int b   = blockIdx.y;   // 0..15
  const int tid = threadIdx.x;
  const int base = b * NFRAMES;
  const float inv_sq2 = 0.7071067811865475f;
  const bool v3 = (tid < NFRAMES - 768);   // tid < 231 -> 4th frame valid

  float f0, f1, f2, f3;
  if (j < 30) {
    const float* e = lmT + (size_t)(2 * j) * NROWS + base;
    const float* o = lmT + (size_t)(2 * j + 1) * NROWS + base;
    f0 = (e[tid]       + o[tid])       * inv_sq2;
    f1 = (e[tid + 256] + o[tid + 256]) * inv_sq2;
    f2 = (e[tid + 512] + o[tid + 512]) * inv_sq2;
    f3 = v3 ? (e[tid + 768] + o[tid + 768]) * inv_sq2 : 0.f;
  } else if (j < 60) {
    const int m = j - 30;
    const float* e = lmT + (size_t)(2 * m) * NROWS + base;
    const float* o = lmT + (size_t)(2 * m + 1) * NROWS + base;
    auto dl = [&](int t) -> float {
      int tp = (t + 1 > NFRAMES - 1) ? (NFRAMES - 1) : (t + 1);
      int tm = (t - 1 < 0) ? 0 : (t - 1);
      return ((e[tp] + o[tp]) - (e[tm] + o[tm])) * inv_sq2;
    };
    f0 = dl(tid);
    f1 = dl(tid + 256);
    f2 = dl(tid + 512);
    f3 = v3 ? dl(tid + 768) : 0.f;
  } else {
    const int m = j - 60;
    const float* e = lmT + (size_t)(2 * m) * NROWS + base;
    const float* o = lmT + (size_t)(2 * m + 1) * NROWS + base;
    f0 = (e[tid]       - o[tid])       * inv_sq2;
    f1 = (e[tid + 256] - o[tid + 256]) * inv_sq2;
    f2 = (e[tid + 512] - o[tid + 512]) * inv_sq2;
    f3 = v3 ? (e[tid + 768] - o[tid + 768]) * inv_sq2 : 0.f;
  }

  // ---- pass 1: mean ----
  float s = f0 + f1 + f2 + f3;
  for (int o2 = 32; o2 > 0; o2 >>= 1) s += __shfl_xor(s, o2, 64);
  if ((tid & 63) == 0) red[tid >> 6] = s;
  __syncthreads();
  float mean = (red[0] + red[1] + red[2] + red[3]) / (float)NFRAMES;
  __syncthreads();

  // ---- pass 2: variance (ddof=1), from registers ----
  float d0 = f0 - mean, d1 = f1 - mean, d2 = f2 - mean;
  float d3 = v3 ? (f3 - mean) : 0.f;
  float s2 = d0 * d0 + d1 * d1 + d2 * d2 + d3 * d3;
  for (int o2 = 32; o2 > 0; o2 >>= 1) s2 += __shfl_xor(s2, o2, 64);
  if ((tid & 63) == 0) red[tid >> 6] = s2;
  __syncthreads();
  float var = (red[0] + red[1] + red[2] + red[3]) / (float)(NFRAMES - 1);

  if (tid == 0) {
    out[b * 180 + j]      = mean;
    out[b * 180 + 90 + j] = sqrtf(var);
  }
}

extern "C" void kernel_launch(void* const* d_in, const int* in_sizes, int n_in,
                              void* d_out, int out_size, void* d_ws, size_t ws_size,
                              hipStream_t stream) {
  const float* wav  = (const float*)d_in[0];   // (16, 441000) f32
  const float* filt = (const float*)d_in[1];   // (60, 1025) f32
  float* out = (float*)d_out;                  // (16, 180) f32

  // ws layout: power bf16 [NROWS][KPAD], filt bf16 [64][KPAD], logmelT f32 [60][NROWS]
  unsigned char* ws = (unsigned char*)d_ws;
  __hip_bfloat16* powr  = (__hip_bfloat16*)(ws);
  size_t off = (size_t)NROWS * KPAD * 2;                      // 33,758,208
  __hip_bfloat16* filtb = (__hip_bfloat16*)(ws + off);
  off += (size_t)64 * KPAD * 2;                               // +135,168
  float* logmelT = (float*)(ws + off);                        // +3,836,160 => ~37.7 MB

  filtconv_kernel<<<64, 256, 0, stream>>>(filt, filtb);
  fft_pow_kernel<<<dim3((NFRAMES + 1) / 2, NBATCH), 256, 0, stream>>>(wav, powr);
  melgemm_kernel<<<NROWS / 16, 256, 0, stream>>>(powr, filtb, logmelT);
  stats_kernel<<<dim3(90, NBATCH), 256, 0, stream>>>(logmelT, out);
}

// Round 7
// 122.884 us; speedup vs baseline: 1.1063x; 1.0440x over previous
//
#include <hip/hip_runtime.h>
#include <hip/hip_bf16.h>
#include <math.h>

#define FRAME_LEN 882
#define FRAME_HOP 441
#define NFFT 2048
#define NFRAMES 999
#define NBATCH 16
#define NMEL 60
#define WAVE_LEN 441000
#define PRE_EMPH 0.97f
#define EPS 1e-10f
#define NROWS (NBATCH * NFRAMES)     // 15984 = 999*16 -> exactly 999 16-row panels
#define KPAD 1056                    // 33*32
#define NKC 33                       // K-chunks of 32
#define PANEL_ELEMS (NKC * 512)      // 16896 elems per 16-row panel (frag-linear)
#define PI_F 3.14159265358979323846f

// LDS float2 index padding: +1 float2 per 16 -> breaks power-of-2 stride conflicts
#define PADI(i) ((i) + ((i) >> 4))

// Frag-linear offset of element (row m in panel, bin k):
// reader (melgemm) lane l reads elems [kc*512 + l*8, +8) <-> (m=l&15, k=kc*32+(l>>4)*8+j)
__device__ __forceinline__ int frag_off(int m, int k) {
  return ((k >> 5) * 512) | (((k >> 3) & 3) * 128) | (m * 8) | (k & 7);
}

__device__ __forceinline__ float2 cadd(float2 a, float2 b){ return make_float2(a.x+b.x, a.y+b.y); }
__device__ __forceinline__ float2 csub(float2 a, float2 b){ return make_float2(a.x-b.x, a.y-b.y); }
__device__ __forceinline__ float2 cmul(float2 a, float2 b){ return make_float2(a.x*b.x - a.y*b.y, a.x*b.y + a.y*b.x); }
__device__ __forceinline__ float2 rotni(float2 z){ return make_float2(z.y, -z.x); }  // z * (-i)

// Three consecutive DIF radix-2 stages (halves 4S,2S,S) in registers.
// Thread owns e_k = q*8S + k*S + r. ALL twiddles derive from t1 = e^{-i*pi*r/(4S)}.
__device__ __forceinline__ void dif_group8(float2* x, float2 t1) {
  const float2 C41 = make_float2(0.7071067812f, -0.7071067812f);
  float2 w0 = t1, w1 = cmul(t1, C41), w2 = rotni(w0), w3 = rotni(w1);
  float2 u, v;
  u=x[0]; v=x[4]; x[0]=cadd(u,v); x[4]=cmul(csub(u,v), w0);
  u=x[1]; v=x[5]; x[1]=cadd(u,v); x[5]=cmul(csub(u,v), w1);
  u=x[2]; v=x[6]; x[2]=cadd(u,v); x[6]=cmul(csub(u,v), w2);
  u=x[3]; v=x[7]; x[3]=cadd(u,v); x[7]=cmul(csub(u,v), w3);
  float2 t2 = cmul(t1, t1), t2r = rotni(t2);
  u=x[0]; v=x[2]; x[0]=cadd(u,v); x[2]=cmul(csub(u,v), t2);
  u=x[1]; v=x[3]; x[1]=cadd(u,v); x[3]=cmul(csub(u,v), t2r);
  u=x[4]; v=x[6]; x[4]=cadd(u,v); x[6]=cmul(csub(u,v), t2);
  u=x[5]; v=x[7]; x[5]=cadd(u,v); x[7]=cmul(csub(u,v), t2r);
  float2 t4 = cmul(t2, t2);
  u=x[0]; v=x[1]; x[0]=cadd(u,v); x[1]=cmul(csub(u,v), t4);
  u=x[2]; v=x[3]; x[2]=cadd(u,v); x[3]=cmul(csub(u,v), t4);
  u=x[4]; v=x[5]; x[4]=cadd(u,v); x[5]=cmul(csub(u,v), t4);
  u=x[6]; v=x[7]; x[6]=cadd(u,v); x[7]=cmul(csub(u,v), t4);
}

// Final two DIF stages (halves 2,1) on 4 consecutive elements: twiddles 1, -i.
__device__ __forceinline__ void dif_radix4(float2* x) {
  float2 y0 = cadd(x[0], x[2]);
  float2 y2 = csub(x[0], x[2]);
  float2 y1 = cadd(x[1], x[3]);
  float2 t3 = csub(x[1], x[3]);
  float2 y3 = rotni(t3);
  x[0] = cadd(y0, y1); x[1] = csub(y0, y1);
  x[2] = cadd(y2, y3); x[3] = csub(y2, y3);
}

// Kernel 1: FFT math identical to R5/R6; power spectra now stored in
// MFMA-FRAGMENT order (frag_off) so melgemm loads are lane-linear coalesced.
__global__ __launch_bounds__(256) void fft_pow_kernel(
    const float* __restrict__ wav, __hip_bfloat16* __restrict__ powrF)
{
  __shared__ float2 lds[NFFT + (NFFT >> 4)];   // 2176 float2 = 17.4 KB
  const int t  = threadIdx.x;
  const int t0 = 2 * blockIdx.x, t1f = t0 + 1;
  const bool has1 = (t1f < NFRAMES);
  const int b = blockIdx.y;
  const float* w = wav + (size_t)b * WAVE_LEN;
  const int s0 = t0 * FRAME_HOP, s1 = t1f * FRAME_HOP;

  float2 x[8];
  {
    float sB, cB, sD, cD;
    __sincosf(6.283185307179586f * (float)t / 881.0f, &sB, &cB);
    __sincosf(6.283185307179586f * 256.0f / 881.0f, &sD, &cD);
    float2 cur  = make_float2(cB, sB);
    float2 step = make_float2(cD, sD);
#pragma unroll
    for (int k = 0; k < 8; ++k) {
      int i = k * 256 + t;
      float v1 = 0.f, v2 = 0.f;
      if (i < FRAME_LEN) {
        float win = 0.54f - 0.46f * cur.x;
        int s = s0 + i;
        float e1 = (s > 0) ? (w[s] - PRE_EMPH * w[s - 1]) : w[s];
        v1 = e1 * win;
        if (has1) {
          int ss = s1 + i;
          v2 = (w[ss] - PRE_EMPH * w[ss - 1]) * win;
        }
      }
      x[k] = make_float2(v1, v2);
      cur = cmul(cur, step);
    }
  }

  {
    float sA, cA;
    __sincosf(-PI_F * (float)t / 1024.0f, &sA, &cA);
    dif_group8(x, make_float2(cA, sA));
  }
#pragma unroll
  for (int k = 0; k < 8; ++k) lds[PADI(k * 256 + t)] = x[k];
  __syncthreads();

  {
    const int q = t >> 5, r = t & 31;
#pragma unroll
    for (int k = 0; k < 8; ++k) x[k] = lds[PADI(q * 256 + k * 32 + r)];
    float sA, cA;
    __sincosf(-PI_F * (float)r / 128.0f, &sA, &cA);
    dif_group8(x, make_float2(cA, sA));
    __syncthreads();
#pragma unroll
    for (int k = 0; k < 8; ++k) lds[PADI(q * 256 + k * 32 + r)] = x[k];
  }
  __syncthreads();

  {
    const int q = t >> 2, r = t & 3;
#pragma unroll
    for (int k = 0; k < 8; ++k) x[k] = lds[PADI(q * 32 + k * 4 + r)];
    float tc = (r == 0) ? 1.0f : (r == 1) ? 0.980785280f : (r == 2) ? 0.923879533f : 0.831469612f;
    float ts = (r == 0) ? 0.0f : (r == 1) ? -0.195090322f : (r == 2) ? -0.382683432f : -0.555570233f;
    dif_group8(x, make_float2(tc, ts));
    __syncthreads();
#pragma unroll
    for (int k = 0; k < 8; ++k) lds[PADI(q * 32 + k * 4 + r)] = x[k];
  }
  __syncthreads();

  {
    float2 xa[4], xb[4];
#pragma unroll
    for (int j = 0; j < 4; ++j) {
      xa[j] = lds[PADI(4 * t + j)];
      xb[j] = lds[PADI(4 * (t + 256) + j)];
    }
    dif_radix4(xa);
    dif_radix4(xb);
    __syncthreads();
#pragma unroll
    for (int j = 0; j < 4; ++j) {
      lds[PADI(4 * t + j)] = xa[j];
      lds[PADI(4 * (t + 256) + j)] = xb[j];
    }
  }
  __syncthreads();

  // ---- power separation + bf16 store in FRAGMENT order ----
  const int r0g = b * NFRAMES + t0;              // global row of frame t0
  const int r1g = r0g + 1;
  __hip_bfloat16* q0 = powrF + (size_t)(r0g >> 4) * PANEL_ELEMS;
  const int m0 = r0g & 15;
  __hip_bfloat16* q1 = powrF + (size_t)(r1g >> 4) * PANEL_ELEMS;
  const int m1 = r1g & 15;
#pragma unroll
  for (int c = 0; c < 5; ++c) {
    int f = t + 256 * c;
    bool valid = (c < 4) || (t == 0);
    if (c == 4) f = 1024;
    if (valid) {
      int j1 = (int)(__brev((unsigned)f) >> 21);
      int j2 = (int)(__brev((unsigned)((NFFT - f) & (NFFT - 1))) >> 21);
      float2 z = lds[PADI(j1)];
      float2 y = lds[PADI(j2)];
      float f1r = z.x + y.x, f1i = z.y - y.y;
      float f2r = z.y + y.y, f2i = y.x - z.x;
      float pw1 = 0.25f * (f1r * f1r + f1i * f1i);
      float pw2 = 0.25f * (f2r * f2r + f2i * f2i);
      q0[frag_off(m0, f)] = __float2bfloat16(pw1);
      if (has1) q1[frag_off(m1, f)] = __float2bfloat16(pw2);
    }
  }
  // zero the K pads (1025..KPAD-1)
  if (t < KPAD - 1025) {
    int f = 1025 + t;
    q0[frag_off(m0, f)] = __float2bfloat16(0.f);
    if (has1) q1[frag_off(m1, f)] = __float2bfloat16(0.f);
  }
}

// Kernel 0: filt (60x1025 f32) -> bf16 in FRAGMENT order, 4 panels of 16 mels,
// pads (mel 60..63, k 1025..) zero.
__global__ __launch_bounds__(256) void filtconv_kernel(
    const float* __restrict__ filt, __hip_bfloat16* __restrict__ filtbF)
{
  const int mm = blockIdx.x;  // 0..63
  __hip_bfloat16* qp = filtbF + (size_t)(mm >> 4) * PANEL_ELEMS;
  const int m = mm & 15;
  for (int k = threadIdx.x; k < KPAD; k += 256) {
    float v = (mm < NMEL && k < 1025) ? filt[mm * 1025 + k] : 0.f;
    qp[frag_off(m, k)] = __float2bfloat16(v);
  }
}

// Kernel 2: mel GEMM, gather-free. Block = one 16-row panel (999 blocks);
// wave w = mel panel w (0..3). Loads are lane-linear: base + kc*1024 + lane*16
// -> one 1 KB coalesced load per fragment. 33 x (2 loads + 1 MFMA) per wave.
typedef __attribute__((ext_vector_type(8))) short short8x;
typedef __attribute__((ext_vector_type(4))) float float4x;

__global__ __launch_bounds__(256) void melgemm_kernel(
    const __hip_bfloat16* __restrict__ powrF,
    const __hip_bfloat16* __restrict__ filtbF,
    float* __restrict__ logmelT)
{
  const int wave = threadIdx.x >> 6, lane = threadIdx.x & 63;
  const int p = blockIdx.x;                       // panel = rows [16p, 16p+16)
  const __hip_bfloat16* pA = powrF + (size_t)p * PANEL_ELEMS + lane * 8;
  const __hip_bfloat16* pB = filtbF + (size_t)wave * PANEL_ELEMS + lane * 8;

  float4x acc0 = {0.f, 0.f, 0.f, 0.f};
  float4x acc1 = {0.f, 0.f, 0.f, 0.f};
#pragma unroll 4
  for (int kc = 0; kc < 16; ++kc) {
    short8x a0 = *(const short8x*)(pA + kc * 512);
    short8x b0 = *(const short8x*)(pB + kc * 512);
    short8x a1 = *(const short8x*)(pA + (kc + 16) * 512);
    short8x b1 = *(const short8x*)(pB + (kc + 16) * 512);
    acc0 = __builtin_amdgcn_mfma_f32_16x16x32_bf16(a0, b0, acc0, 0, 0, 0);
    acc1 = __builtin_amdgcn_mfma_f32_16x16x32_bf16(a1, b1, acc1, 0, 0, 0);
  }
  {
    short8x a = *(const short8x*)(pA + 32 * 512);
    short8x bf = *(const short8x*)(pB + 32 * 512);
    acc0 = __builtin_amdgcn_mfma_f32_16x16x32_bf16(a, bf, acc0, 0, 0, 0);
  }

  // C/D layout: col = lane&15 (mel), row = (lane>>4)*4 + reg (panel row)
  const int mel = wave * 16 + (lane & 15);
  const int rsub = (lane >> 4) * 4;
  if (mel < NMEL) {
#pragma unroll
    for (int reg = 0; reg < 4; ++reg) {
      int row = p * 16 + rsub + reg;
      float vv = acc0[reg] + acc1[reg];
      logmelT[(size_t)mel * NROWS + row] = __logf(vv + EPS);
    }
  }
}

// Kernel 3: stats on transposed logmel — one block per (feature j, batch b);
// coalesced 4-B reads, static registers, two-pass mean/std (ddof=1).
__global__ __launch_bounds__(256) void stats_kernel(
    const float* __restrict__ lmT, float* __restrict__ out)
{
  __shared__ float red[4];
  const int j   = blockIdx.x;   // 0..89
  const int b   = blockIdx.y;   // 0..15
  const int tid = threadIdx.x;
  const int base = b * NFRAMES;
  const float inv_sq2 = 0.7071067811865475f;
  const bool v3 = (tid < NFRAMES - 768);

  float f0, f1, f2, f3;
  if (j < 30) {
    const float* e = lmT + (size_t)(2 * j) * NROWS + base;
    const float* o = lmT + (size_t)(2 * j + 1) * NROWS + base;
    f0 = (e[tid]       + o[tid])       * inv_sq2;
    f1 = (e[tid + 256] + o[tid + 256]) * inv_sq2;
    f2 = (e[tid + 512] + o[tid + 512]) * inv_sq2;
    f3 = v3 ? (e[tid + 768] + o[tid + 768]) * inv_sq2 : 0.f;
  } else if (j < 60) {
    const int m = j - 30;
    const float* e = lmT + (size_t)(2 * m) * NROWS + base;
    const float* o = lmT + (size_t)(2 * m + 1) * NROWS + base;
    auto dl = [&](int t) -> float {
      int tp = (t + 1 > NFRAMES - 1) ? (NFRAMES - 1) : (t + 1);
      int tm = (t - 1 < 0) ? 0 : (t - 1);
      return ((e[tp] + o[tp]) - (e[tm] + o[tm])) * inv_sq2;
    };
    f0 = dl(tid);
    f1 = dl(tid + 256);
    f2 = dl(tid + 512);
    f3 = v3 ? dl(tid + 768) : 0.f;
  } else {
    const int m = j - 60;
    const float* e = lmT + (size_t)(2 * m) * NROWS + base;
    const float* o = lmT + (size_t)(2 * m + 1) * NROWS + base;
    f0 = (e[tid]       - o[tid])       * inv_sq2;
    f1 = (e[tid + 256] - o[tid + 256]) * inv_sq2;
    f2 = (e[tid + 512] - o[tid + 512]) * inv_sq2;
    f3 = v3 ? (e[tid + 768] - o[tid + 768]) * inv_sq2 : 0.f;
  }

  float s = f0 + f1 + f2 + f3;
  for (int o2 = 32; o2 > 0; o2 >>= 1) s += __shfl_xor(s, o2, 64);
  if ((tid & 63) == 0) red[tid >> 6] = s;
  __syncthreads();
  float mean = (red[0] + red[1] + red[2] + red[3]) / (float)NFRAMES;
  __syncthreads();

  float d0 = f0 - mean, d1 = f1 - mean, d2 = f2 - mean;
  float d3 = v3 ? (f3 - mean) : 0.f;
  float s2 = d0 * d0 + d1 * d1 + d2 * d2 + d3 * d3;
  for (int o2 = 32; o2 > 0; o2 >>= 1) s2 += __shfl_xor(s2, o2, 64);
  if ((tid & 63) == 0) red[tid >> 6] = s2;
  __syncthreads();
  float var = (red[0] + red[1] + red[2] + red[3]) / (float)(NFRAMES - 1);

  if (tid == 0) {
    out[b * 180 + j]      = mean;
    out[b * 180 + 90 + j] = sqrtf(var);
  }
}

extern "C" void kernel_launch(void* const* d_in, const int* in_sizes, int n_in,
                              void* d_out, int out_size, void* d_ws, size_t ws_size,
                              hipStream_t stream) {
  const float* wav  = (const float*)d_in[0];   // (16, 441000) f32
  const float* filt = (const float*)d_in[1];   // (60, 1025) f32
  float* out = (float*)d_out;                  // (16, 180) f32

  // ws: powrF bf16 [999 panels][16896], filtbF bf16 [4][16896], logmelT f32 [60][NROWS]
  unsigned char* ws = (unsigned char*)d_ws;
  __hip_bfloat16* powrF  = (__hip_bfloat16*)(ws);
  size_t off = (size_t)999 * PANEL_ELEMS * 2;                 // 33,758,208
  __hip_bfloat16* filtbF = (__hip_bfloat16*)(ws + off);
  off += (size_t)4 * PANEL_ELEMS * 2;                         // +135,168
  float* logmelT = (float*)(ws + off);                        // +3,836,160 => ~37.7 MB

  filtconv_kernel<<<64, 256, 0, stream>>>(filt, filtbF);
  fft_pow_kernel<<<dim3((NFRAMES + 1) / 2, NBATCH), 256, 0, stream>>>(wav, powrF);
  melgemm_kernel<<<999, 256, 0, stream>>>(powrF, filtbF, logmelT);
  stats_kernel<<<dim3(90, NBATCH), 256, 0, stream>>>(logmelT, out);
}

// Round 8
// 121.771 us; speedup vs baseline: 1.1164x; 1.0091x over previous
//
#include <hip/hip_runtime.h>
#include <hip/hip_bf16.h>
#include <math.h>

#define FRAME_LEN 882
#define FRAME_HOP 441
#define NFFT 2048
#define NFRAMES 999
#define NBATCH 16
#define NMEL 60
#define WAVE_LEN 441000
#define PRE_EMPH 0.97f
#define EPS 1e-10f
#define NROWS (NBATCH * NFRAMES)     // 15984 = 999*16 -> exactly 999 16-row panels
#define KPAD 1056                    // 33*32
#define NKC 33                       // K-chunks of 32
#define PANEL_ELEMS (NKC * 512)      // 16896 elems per 16-row panel (frag-linear)
#define PI_F 3.14159265358979323846f

// LDS float2 index padding: +1 float2 per 16 -> breaks power-of-2 stride conflicts
#define PADI(i) ((i) + ((i) >> 4))

// Frag-linear offset of element (row m in panel, bin k):
// reader (melgemm) lane l reads elems [kc*512 + l*8, +8) <-> (m=l&15, k=kc*32+(l>>4)*8+j)
__device__ __forceinline__ int frag_off(int m, int k) {
  return ((k >> 5) * 512) | (((k >> 3) & 3) * 128) | (m * 8) | (k & 7);
}

// Packed complex type: ext_vector float2 -> VOP3P v_pk_{add,mul,fma}_f32.
typedef float vf2 __attribute__((ext_vector_type(2)));
__device__ __forceinline__ vf2 mkv(float x, float y){ vf2 r; r.x = x; r.y = y; return r; }
__device__ __forceinline__ vf2 cmul(vf2 a, vf2 b){ return a.xx * b + mkv(-a.y, a.y) * b.yx; }
__device__ __forceinline__ vf2 rotni(vf2 z){ return mkv(z.y, -z.x); }  // z * (-i)

// Three consecutive DIF radix-2 stages (halves 4S,2S,S) in registers.
// Thread owns e_k = q*8S + k*S + r. ALL twiddles derive from t1 = e^{-i*pi*r/(4S)}.
__device__ __forceinline__ void dif_group8(vf2* x, vf2 t1) {
  const vf2 C41 = mkv(0.7071067812f, -0.7071067812f);
  vf2 w0 = t1, w1 = cmul(t1, C41), w2 = rotni(w0), w3 = rotni(w1);
  vf2 u, v;
  u=x[0]; v=x[4]; x[0]=u+v; x[4]=cmul(u-v, w0);
  u=x[1]; v=x[5]; x[1]=u+v; x[5]=cmul(u-v, w1);
  u=x[2]; v=x[6]; x[2]=u+v; x[6]=cmul(u-v, w2);
  u=x[3]; v=x[7]; x[3]=u+v; x[7]=cmul(u-v, w3);
  vf2 t2 = cmul(t1, t1), t2r = rotni(t2);
  u=x[0]; v=x[2]; x[0]=u+v; x[2]=cmul(u-v, t2);
  u=x[1]; v=x[3]; x[1]=u+v; x[3]=cmul(u-v, t2r);
  u=x[4]; v=x[6]; x[4]=u+v; x[6]=cmul(u-v, t2);
  u=x[5]; v=x[7]; x[5]=u+v; x[7]=cmul(u-v, t2r);
  vf2 t4 = cmul(t2, t2);
  u=x[0]; v=x[1]; x[0]=u+v; x[1]=cmul(u-v, t4);
  u=x[2]; v=x[3]; x[2]=u+v; x[3]=cmul(u-v, t4);
  u=x[4]; v=x[5]; x[4]=u+v; x[5]=cmul(u-v, t4);
  u=x[6]; v=x[7]; x[6]=u+v; x[7]=cmul(u-v, t4);
}

// Final two DIF stages (halves 2,1) on 4 consecutive elements: twiddles 1, -i.
__device__ __forceinline__ void dif_radix4(vf2* x) {
  vf2 y0 = x[0] + x[2];
  vf2 y2 = x[0] - x[2];
  vf2 y1 = x[1] + x[3];
  vf2 y3 = rotni(x[1] - x[3]);
  x[0] = y0 + y1; x[1] = y0 - y1;
  x[2] = y2 + y3; x[3] = y2 - y3;
}

// Kernel 1: FFT math identical to R7 but on packed (VOP3P) complex type;
// power spectra stored in MFMA-fragment order for the gather-free GEMM.
__global__ __launch_bounds__(256) void fft_pow_kernel(
    const float* __restrict__ wav, __hip_bfloat16* __restrict__ powrF)
{
  __shared__ vf2 lds[NFFT + (NFFT >> 4)];   // 2176 vf2 = 17.4 KB
  const int t  = threadIdx.x;
  const int t0 = 2 * blockIdx.x, t1f = t0 + 1;
  const bool has1 = (t1f < NFRAMES);
  const int b = blockIdx.y;
  const float* w = wav + (size_t)b * WAVE_LEN;
  const int s0 = t0 * FRAME_HOP;
  // clamp s1 so the (unused) last-frame lane reads stay in bounds
  int s1 = t1f * FRAME_HOP;
  if (s1 > WAVE_LEN - FRAME_LEN) s1 = WAVE_LEN - FRAME_LEN;

  vf2 x[8];
  // ---- load + pre-emphasis + Hamming (cos via one sincos + recurrence) ----
  {
    float sB, cB, sD, cD;
    __sincosf(6.283185307179586f * (float)t / 881.0f, &sB, &cB);
    __sincosf(6.283185307179586f * 256.0f / 881.0f, &sD, &cD);
    vf2 cur  = mkv(cB, sB);
    vf2 step = mkv(cD, sD);
#pragma unroll
    for (int k = 0; k < 8; ++k) {
      int i = k * 256 + t;
      float v1 = 0.f, v2 = 0.f;
      if (i < FRAME_LEN) {
        float win = 0.54f - 0.46f * cur.x;
        int s = s0 + i;
        float e1 = (s > 0) ? (w[s] - PRE_EMPH * w[s - 1]) : w[s];
        v1 = e1 * win;
        int ss = s1 + i;                    // ss >= 441 > 0 always
        v2 = (w[ss] - PRE_EMPH * w[ss - 1]) * win;
      }
      x[k] = mkv(v1, v2);
      cur = cmul(cur, step);
    }
  }

  // ---- G0: halves 1024,512,256 (S=256, r=t): t1 = e^{-i*pi*t/1024}
  {
    float sA, cA;
    __sincosf(-PI_F * (float)t / 1024.0f, &sA, &cA);
    dif_group8(x, mkv(cA, sA));
  }
#pragma unroll
  for (int k = 0; k < 8; ++k) lds[PADI(k * 256 + t)] = x[k];
  __syncthreads();

  // ---- G1: halves 128,64,32 (S=32): t1 = e^{-i*pi*r/128}, r = t&31
  {
    const int q = t >> 5, r = t & 31;
#pragma unroll
    for (int k = 0; k < 8; ++k) x[k] = lds[PADI(q * 256 + k * 32 + r)];
    float sA, cA;
    __sincosf(-PI_F * (float)r / 128.0f, &sA, &cA);
    dif_group8(x, mkv(cA, sA));
    __syncthreads();
#pragma unroll
    for (int k = 0; k < 8; ++k) lds[PADI(q * 256 + k * 32 + r)] = x[k];
  }
  __syncthreads();

  // ---- G2: halves 16,8,4 (S=4): t1 = e^{-i*pi*r/16}, r = t&3 -> const table
  {
    const int q = t >> 2, r = t & 3;
#pragma unroll
    for (int k = 0; k < 8; ++k) x[k] = lds[PADI(q * 32 + k * 4 + r)];
    float tc = (r == 0) ? 1.0f : (r == 1) ? 0.980785280f : (r == 2) ? 0.923879533f : 0.831469612f;
    float ts = (r == 0) ? 0.0f : (r == 1) ? -0.195090322f : (r == 2) ? -0.382683432f : -0.555570233f;
    dif_group8(x, mkv(tc, ts));
    __syncthreads();
#pragma unroll
    for (int k = 0; k < 8; ++k) lds[PADI(q * 32 + k * 4 + r)] = x[k];
  }
  __syncthreads();

  // ---- G3: halves 2,1 — two radix-4 groups of 4 consecutive elements
  {
    vf2 xa[4], xb[4];
#pragma unroll
    for (int j = 0; j < 4; ++j) {
      xa[j] = lds[PADI(4 * t + j)];
      xb[j] = lds[PADI(4 * (t + 256) + j)];
    }
    dif_radix4(xa);
    dif_radix4(xb);
    __syncthreads();
#pragma unroll
    for (int j = 0; j < 4; ++j) {
      lds[PADI(4 * t + j)] = xa[j];
      lds[PADI(4 * (t + 256) + j)] = xb[j];
    }
  }
  __syncthreads();

  // ---- power separation + bf16 store in FRAGMENT order ----
  const int r0g = b * NFRAMES + t0;
  const int r1g = r0g + 1;
  __hip_bfloat16* q0 = powrF + (size_t)(r0g >> 4) * PANEL_ELEMS;
  const int m0 = r0g & 15;
  __hip_bfloat16* q1 = powrF + (size_t)(r1g >> 4) * PANEL_ELEMS;
  const int m1 = r1g & 15;
#pragma unroll
  for (int c = 0; c < 4; ++c) {
    int f = t + 256 * c;
    int j1 = (int)(__brev((unsigned)f) >> 21);
    int j2 = (int)(__brev((unsigned)((NFFT - f) & (NFFT - 1))) >> 21);
    vf2 z = lds[PADI(j1)];
    vf2 y = lds[PADI(j2)];
    float f1r = z.x + y.x, f1i = z.y - y.y;
    float f2r = z.y + y.y, f2i = y.x - z.x;
    float pw1 = 0.25f * (f1r * f1r + f1i * f1i);
    float pw2 = 0.25f * (f2r * f2r + f2i * f2i);
    q0[frag_off(m0, f)] = __float2bfloat16(pw1);
    if (has1) q1[frag_off(m1, f)] = __float2bfloat16(pw2);
  }
  if (t == 0) {
    vf2 z = lds[PADI(1)];            // brev(1024) = 1; Z[1024] self-conjugate pair
    q0[frag_off(m0, 1024)] = __float2bfloat16(z.x * z.x);
    if (has1) q1[frag_off(m1, 1024)] = __float2bfloat16(z.y * z.y);
  }
  // zero the K pads (1025..KPAD-1)
  if (t < KPAD - 1025) {
    int f = 1025 + t;
    q0[frag_off(m0, f)] = __float2bfloat16(0.f);
    if (has1) q1[frag_off(m1, f)] = __float2bfloat16(0.f);
  }
}

// Kernel 0: filt (60x1025 f32) -> bf16 in FRAGMENT order, 4 panels of 16 mels.
__global__ __launch_bounds__(256) void filtconv_kernel(
    const float* __restrict__ filt, __hip_bfloat16* __restrict__ filtbF)
{
  const int mm = blockIdx.x;  // 0..63
  __hip_bfloat16* qp = filtbF + (size_t)(mm >> 4) * PANEL_ELEMS;
  const int m = mm & 15;
  for (int k = threadIdx.x; k < KPAD; k += 256) {
    float v = (mm < NMEL && k < 1025) ? filt[mm * 1025 + k] : 0.f;
    qp[frag_off(m, k)] = __float2bfloat16(v);
  }
}

// Kernel 2: mel GEMM, gather-free (fragment-order operands), unchanged from R7.
typedef __attribute__((ext_vector_type(8))) short short8x;
typedef __attribute__((ext_vector_type(4))) float float4x;

__global__ __launch_bounds__(256) void melgemm_kernel(
    const __hip_bfloat16* __restrict__ powrF,
    const __hip_bfloat16* __restrict__ filtbF,
    float* __restrict__ logmelT)
{
  const int wave = threadIdx.x >> 6, lane = threadIdx.x & 63;
  const int p = blockIdx.x;                       // panel = rows [16p, 16p+16)
  const __hip_bfloat16* pA = powrF + (size_t)p * PANEL_ELEMS + lane * 8;
  const __hip_bfloat16* pB = filtbF + (size_t)wave * PANEL_ELEMS + lane * 8;

  float4x acc0 = {0.f, 0.f, 0.f, 0.f};
  float4x acc1 = {0.f, 0.f, 0.f, 0.f};
#pragma unroll 4
  for (int kc = 0; kc < 16; ++kc) {
    short8x a0 = *(const short8x*)(pA + kc * 512);
    short8x b0 = *(const short8x*)(pB + kc * 512);
    short8x a1 = *(const short8x*)(pA + (kc + 16) * 512);
    short8x b1 = *(const short8x*)(pB + (kc + 16) * 512);
    acc0 = __builtin_amdgcn_mfma_f32_16x16x32_bf16(a0, b0, acc0, 0, 0, 0);
    acc1 = __builtin_amdgcn_mfma_f32_16x16x32_bf16(a1, b1, acc1, 0, 0, 0);
  }
  {
    short8x a = *(const short8x*)(pA + 32 * 512);
    short8x bf = *(const short8x*)(pB + 32 * 512);
    acc0 = __builtin_amdgcn_mfma_f32_16x16x32_bf16(a, bf, acc0, 0, 0, 0);
  }

  // C/D layout: col = lane&15 (mel), row = (lane>>4)*4 + reg (panel row)
  const int mel = wave * 16 + (lane & 15);
  const int rsub = (lane >> 4) * 4;
  if (mel < NMEL) {
#pragma unroll
    for (int reg = 0; reg < 4; ++reg) {
      int row = p * 16 + rsub + reg;
      float vv = acc0[reg] + acc1[reg];
      logmelT[(size_t)mel * NROWS + row] = __logf(vv + EPS);
    }
  }
}

// Kernel 3: stats on transposed logmel — one block per (feature j, batch b);
// coalesced 4-B reads, static registers, two-pass mean/std (ddof=1).
__global__ __launch_bounds__(256) void stats_kernel(
    const float* __restrict__ lmT, float* __restrict__ out)
{
  __shared__ float red[4];
  const int j   = blockIdx.x;   // 0..89
  const int b   = blockIdx.y;   // 0..15
  const int tid = threadIdx.x;
  const int base = b * NFRAMES;
  const float inv_sq2 = 0.7071067811865475f;
  const bool v3 = (tid < NFRAMES - 768);

  float f0, f1, f2, f3;
  if (j < 30) {
    const float* e = lmT + (size_t)(2 * j) * NROWS + base;
    const float* o = lmT + (size_t)(2 * j + 1) * NROWS + base;
    f0 = (e[tid]       + o[tid])       * inv_sq2;
    f1 = (e[tid + 256] + o[tid + 256]) * inv_sq2;
    f2 = (e[tid + 512] + o[tid + 512]) * inv_sq2;
    f3 = v3 ? (e[tid + 768] + o[tid + 768]) * inv_sq2 : 0.f;
  } else if (j < 60) {
    const int m = j - 30;
    const float* e = lmT + (size_t)(2 * m) * NROWS + base;
    const float* o = lmT + (size_t)(2 * m + 1) * NROWS + base;
    auto dl = [&](int t) -> float {
      int tp = (t + 1 > NFRAMES - 1) ? (NFRAMES - 1) : (t + 1);
      int tm = (t - 1 < 0) ? 0 : (t - 1);
      return ((e[tp] + o[tp]) - (e[tm] + o[tm])) * inv_sq2;
    };
    f0 = dl(tid);
    f1 = dl(tid + 256);
    f2 = dl(tid + 512);
    f3 = v3 ? dl(tid + 768) : 0.f;
  } else {
    const int m = j - 60;
    const float* e = lmT + (size_t)(2 * m) * NROWS + base;
    const float* o = lmT + (size_t)(2 * m + 1) * NROWS + base;
    f0 = (e[tid]       - o[tid])       * inv_sq2;
    f1 = (e[tid + 256] - o[tid + 256]) * inv_sq2;
    f2 = (e[tid + 512] - o[tid + 512]) * inv_sq2;
    f3 = v3 ? (e[tid + 768] - o[tid + 768]) * inv_sq2 : 0.f;
  }

  float s = f0 + f1 + f2 + f3;
  for (int o2 = 32; o2 > 0; o2 >>= 1) s += __shfl_xor(s, o2, 64);
  if ((tid & 63) == 0) red[tid >> 6] = s;
  __syncthreads();
  float mean = (red[0] + red[1] + red[2] + red[3]) / (float)NFRAMES;
  __syncthreads();

  float d0 = f0 - mean, d1 = f1 - mean, d2 = f2 - mean;
  float d3 = v3 ? (f3 - mean) : 0.f;
  float s2 = d0 * d0 + d1 * d1 + d2 * d2 + d3 * d3;
  for (int o2 = 32; o2 > 0; o2 >>= 1) s2 += __shfl_xor(s2, o2, 64);
  if ((tid & 63) == 0) red[tid >> 6] = s2;
  __syncthreads();
  float var = (red[0] + red[1] + red[2] + red[3]) / (float)(NFRAMES - 1);

  if (tid == 0) {
    out[b * 180 + j]      = mean;
    out[b * 180 + 90 + j] = sqrtf(var);
  }
}

extern "C" void kernel_launch(void* const* d_in, const int* in_sizes, int n_in,
                              void* d_out, int out_size, void* d_ws, size_t ws_size,
                              hipStream_t stream) {
  const float* wav  = (const float*)d_in[0];   // (16, 441000) f32
  const float* filt = (const float*)d_in[1];   // (60, 1025) f32
  float* out = (float*)d_out;                  // (16, 180) f32

  // ws: powrF bf16 [999 panels][16896], filtbF bf16 [4][16896], logmelT f32 [60][NROWS]
  unsigned char* ws = (unsigned char*)d_ws;
  __hip_bfloat16* powrF  = (__hip_bfloat16*)(ws);
  size_t off = (size_t)999 * PANEL_ELEMS * 2;                 // 33,758,208
  __hip_bfloat16* filtbF = (__hip_bfloat16*)(ws + off);
  off += (size_t)4 * PANEL_ELEMS * 2;                         // +135,168
  float* logmelT = (float*)(ws + off);                        // +3,836,160 => ~37.7 MB

  filtconv_kernel<<<64, 256, 0, stream>>>(filt, filtbF);
  fft_pow_kernel<<<dim3((NFRAMES + 1) / 2, NBATCH), 256, 0, stream>>>(wav, powrF);
  melgemm_kernel<<<999, 256, 0, stream>>>(powrF, filtbF, logmelT);
  stats_kernel<<<dim3(90, NBATCH), 256, 0, stream>>>(logmelT, out);
}